// Round 1
// baseline (933.514 us; speedup 1.0000x reference)
//
// TemporalAttention on MI355X (gfx950) — Round 4 (resubmit: container infra failure).
//  - V^T (z=2) GEMM epilogue: LDS transpose -> coalesced 128B-row dwordx4 stores
//    (was 64x 8B stores at 2KB stride = up to 8x TCC sector write amplification).
//  - 1/8 attention scale folded into w_q convert (no epilogue mul).
//  - attn: division-free zero fills, half4 ctx store.
//  - 5 dispatches: cvt_all, rvT, qkv gemm (z=3), attn, out gemm.

#include <hip/hip_runtime.h>
#include <cstdint>
#include <cstddef>

#define S_LEN 1024
#define DMODEL 1024
#define NHEADS 16
#define DK 64
#define BATCH 8
#define PUS 296    // Pu row stride (halves)
#define PBS 272    // Pband row stride (halves)
#define RELS 257   // RelL row stride (floats)

using half8_t  = __attribute__((ext_vector_type(8))) _Float16;
using half4_t  = __attribute__((ext_vector_type(4))) _Float16;
using float4_t = __attribute__((ext_vector_type(4))) float;

__device__ __forceinline__ void async16(const void* g, void* l) {
  __builtin_amdgcn_global_load_lds(
      (const __attribute__((address_space(1))) unsigned int*)g,
      (__attribute__((address_space(3))) unsigned int*)l, 16, 0, 0);
}

// ---------------- merged fp32 -> fp16 convert (8 regions) ----------------
struct CvtRegion { const float* src; _Float16* dst; int n4; float scale; };
struct CvtArgs { CvtRegion r[8]; };

__global__ __launch_bounds__(256) void cvt_all_kernel(CvtArgs a) {
  CvtRegion reg = a.r[blockIdx.y];
  const int stride = gridDim.x * 256;
  for (int i = blockIdx.x * 256 + threadIdx.x; i < reg.n4; i += stride) {
    float4_t f = ((const float4_t*)reg.src)[i];
    half4_t h;
    h[0] = (_Float16)(f[0] * reg.scale); h[1] = (_Float16)(f[1] * reg.scale);
    h[2] = (_Float16)(f[2] * reg.scale); h[3] = (_Float16)(f[3] * reg.scale);
    ((half4_t*)reg.dst)[i] = h;
  }
}

// rvT[d][j] = rel_v[j+1][d] for j in [0,255), col 255 = 0.
__global__ void build_rvT_kernel(const float* __restrict__ relv, _Float16* __restrict__ rvT) {
  int d = blockIdx.x;
  int j = threadIdx.x;
  rvT[d * 256 + j] = (j < 255) ? (_Float16)relv[(size_t)(j + 1) * DK + d] : (_Float16)0.f;
}

// ---------------- GEMM core: acc = A[128,K] * B[128,K]^T tile ----------------
__device__ __forceinline__ void gemm_core(
    const _Float16* __restrict__ A, const _Float16* __restrict__ B,
    _Float16* smem, float4_t acc[4][4], int m0, int n0,
    int wave, int lane, int quad, int ln, int wm, int wn)
{
  _Float16* As = smem;
  _Float16* Bs = smem + 4096;
#pragma unroll
  for (int i = 0; i < 4; i++)
#pragma unroll
    for (int j = 0; j < 4; j++) { acc[i][j][0]=0.f; acc[i][j][1]=0.f; acc[i][j][2]=0.f; acc[i][j][3]=0.f; }

  for (int k0 = 0; k0 < 1024; k0 += 32) {
#pragma unroll
    for (int hh = 0; hh < 2; hh++) {
      int slot = hh * 256 + wave * 64 + lane;
      int m = slot >> 2, qc = slot & 3;
      int qg = qc ^ (m & 3);
      async16(A + (size_t)(m0 + m) * 1024 + k0 + qg * 8,
              As + (size_t)(hh * 256 + wave * 64) * 8);
      async16(B + (size_t)(n0 + m) * 1024 + k0 + qg * 8,
              Bs + (size_t)(hh * 256 + wave * 64) * 8);
    }
    __syncthreads();
    half8_t af[4], bf[4];
#pragma unroll
    for (int t = 0; t < 4; t++) {
      int mm = wm + t * 16 + ln;
      af[t] = *(const half8_t*)(As + mm * 32 + ((quad ^ (mm & 3)) * 8));
      int nn = wn + t * 16 + ln;
      bf[t] = *(const half8_t*)(Bs + nn * 32 + ((quad ^ (nn & 3)) * 8));
    }
#pragma unroll
    for (int i = 0; i < 4; i++)
#pragma unroll
      for (int j = 0; j < 4; j++)
        acc[i][j] = __builtin_amdgcn_mfma_f32_16x16x32_f16(af[i], bf[j], acc[i][j], 0, 0, 0);
    __syncthreads();
  }
}

// ---------------- fused QKV projection (grid.z = 0:Q 1:K 2:V) ----------------
struct QkvArgs {
  const _Float16* A[3];
  const _Float16* B[3];
  _Float16* dst[3];
};

__global__ __launch_bounds__(256) void gemm_qkv(QkvArgs qa) {
  __shared__ _Float16 smem[8192];
  const int tid = threadIdx.x;
  const int wave = tid >> 6, lane = tid & 63;
  const int quad = lane >> 4, ln = lane & 15;
  const int m0 = blockIdx.x * 128, n0 = blockIdx.y * 128;
  const int wm = (wave >> 1) * 64, wn = (wave & 1) * 64;
  const int z = blockIdx.z;

  float4_t acc[4][4];
  gemm_core(qa.A[z], qa.B[z], smem, acc, m0, n0, wave, lane, quad, ln, wm, wn);

  _Float16* o = qa.dst[z];
  if (z < 2) {
    // [B,H,S,dk] via LDS transpose, coalesced 16B stores. (Q pre-scaled via w_q)
    _Float16* T = smem + wave * 1152;               // 16 x 72
    size_t headoff = ((size_t)((n0 + wn) >> 6)) << 16;
#pragma unroll
    for (int i = 0; i < 4; i++) {
#pragma unroll
      for (int j = 0; j < 4; j++)
#pragma unroll
        for (int r = 0; r < 4; r++)
          T[(quad * 4 + r) * 72 + j * 16 + ln] = (_Float16)acc[i][j][r];
      int mbase = m0 + wm + i * 16;
#pragma unroll
      for (int p = 0; p < 2; p++) {
        int row = p * 8 + (lane >> 3);
        int cc = (lane & 7) * 8;
        half8_t hv = *(const half8_t*)(T + row * 72 + cc);
        int token = mbase + row;
        size_t idx = ((size_t)(token >> 10) << 20) | headoff
                   | ((size_t)(token & 1023) << 6) | (size_t)cc;
        *(half8_t*)(o + idx) = hv;
      }
    }
  } else {
    // V^T per head [B,H,dk,S]: per j-slice LDS transpose -> 128B-row stores.
    _Float16* T = smem + wave * 1160;               // 16 (d) x 72 (token+pad)
    const int tok0 = m0 + wm;                       // 64 tokens, same batch
    const size_t base = ((size_t)(tok0 >> 10) << 20)
                      | (((size_t)((n0 + wn) >> 6)) << 16)
                      | (size_t)(tok0 & 1023);
#pragma unroll
    for (int j = 0; j < 4; j++) {
#pragma unroll
      for (int i = 0; i < 4; i++)
#pragma unroll
        for (int r = 0; r < 4; r++)
          T[ln * 72 + i * 16 + quad * 4 + r] = (_Float16)acc[i][j][r];
#pragma unroll
      for (int p = 0; p < 2; p++) {
        int drow = p * 8 + (lane >> 3);
        int cc = (lane & 7) * 8;
        half8_t hv = *(const half8_t*)(T + drow * 72 + cc);
        size_t idx = base + (((size_t)(j * 16 + drow)) << 10) + (size_t)cc;
        *(half8_t*)(o + idx) = hv;
      }
    }
  }
}

// ---------------- output projection (fp32 + bias) ----------------
__global__ __launch_bounds__(256) void gemm_out(
    const _Float16* __restrict__ A, const _Float16* __restrict__ B,
    float* __restrict__ o, const float* __restrict__ bias)
{
  __shared__ _Float16 smem[8192];
  const int tid = threadIdx.x;
  const int wave = tid >> 6, lane = tid & 63;
  const int quad = lane >> 4, ln = lane & 15;
  const int m0 = blockIdx.x * 128, n0 = blockIdx.y * 128;
  const int wm = (wave >> 1) * 64, wn = (wave & 1) * 64;

  float4_t acc[4][4];
  gemm_core(A, B, smem, acc, m0, n0, wave, lane, quad, ln, wm, wn);

#pragma unroll
  for (int i = 0; i < 4; i++)
#pragma unroll
    for (int j = 0; j < 4; j++) {
      int nn = n0 + wn + j * 16 + ln;
      float bb = bias[nn];
#pragma unroll
      for (int r = 0; r < 4; r++) {
        int mm = m0 + wm + i * 16 + quad * 4 + r;
        o[(size_t)mm * 1024 + nn] = acc[i][j][r] + bb;
      }
    }
}

// ---------------- fused windowed attention ----------------
__global__ __launch_bounds__(256, 4) void attn4_kernel(
    const _Float16* __restrict__ Qh, const _Float16* __restrict__ Kh,
    const _Float16* __restrict__ VtG, const _Float16* __restrict__ relk,
    const _Float16* __restrict__ rvT, const float* __restrict__ decay,
    float* __restrict__ attn_out, _Float16* __restrict__ ctx)
{
  __shared__ float    RelL[16 * RELS];
  __shared__ _Float16 Pu[16 * PUS];
  __shared__ _Float16 Pband[16 * PBS];
  __shared__ float    ctxLds[16 * 64];
  __shared__ float    statsM[4][16];
  __shared__ float    statsZ[4][16];

  const int tid = threadIdx.x;
  const int wave = tid >> 6, lane = tid & 63;
  const int quad = lane >> 4, ln = lane & 15;
  const int bid = blockIdx.x;
  const int b = bid >> 10, h = (bid >> 6) & 15, lt = bid & 63;
  const int l0 = lt * 16;
  const int bh = b * NHEADS + h;
  const _Float16* Qb = Qh + ((size_t)bh << 16);
  const _Float16* Kb = Kh + ((size_t)bh << 16);
  const _Float16* Vb = VtG + ((size_t)bh << 16);
  float* arow = attn_out + ((size_t)bh << 20) + (size_t)l0 * S_LEN;
  const float dec = decay[h];

  const int rlo = (l0 > 127) ? ((l0 - 127) & ~15) : 0;
  int rhi = (l0 + 158) & ~15;
  if (rhi > S_LEN) rhi = S_LEN;
  const int W = rhi - rlo;
  const int nT = W >> 4;
  const int ts = (wave * nT) >> 2;
  const int te = ((wave + 1) * nT) >> 2;

  // ---- zero fills (division-free: row-outer) ----
  const float4_t fz = {0.f, 0.f, 0.f, 0.f};
  {
    int w4l = rlo >> 2;
    int w4r = (S_LEN - rhi) >> 2;
#pragma unroll 1
    for (int row = 0; row < 16; row++) {
      float* ar = arow + (size_t)row * S_LEN;
      for (int c4 = tid; c4 < w4l; c4 += 256)
        __builtin_nontemporal_store(fz, (float4_t*)(ar + c4 * 4));
      float* ar2 = ar + rhi;
      for (int c4 = tid; c4 < w4r; c4 += 256)
        __builtin_nontemporal_store(fz, (float4_t*)(ar2 + c4 * 4));
    }
  }
  ((float4_t*)ctxLds)[tid] = fz;
  {
    const half8_t hz = {};
    for (int i = tid; i < 16 * PBS / 8; i += 256) ((half8_t*)Pband)[i] = hz;
    for (int i = tid; i < 16 * PUS / 8; i += 256) ((half8_t*)Pu)[i] = hz;
  }

  // ---- Q fragments (pre-scaled by 1/8 via w_q) ----
  half8_t aq[2];
  {
    const _Float16* qp = Qb + (size_t)(l0 + ln) * DK + quad * 8;
    aq[0] = *(const half8_t*)(qp);
    aq[1] = *(const half8_t*)(qp + 32);
  }

  // ---- RelL[l][j] = (Q/8).(8*rel_k[j+1]) - dec*|j-127| ----
#pragma unroll
  for (int s = 0; s < 4; s++) {
    int nt = wave * 4 + s;
    int j = nt * 16 + ln;
    const _Float16* bp = relk + (size_t)(j + 1) * DK + quad * 8;
    half8_t b0 = *(const half8_t*)bp;
    half8_t b1 = *(const half8_t*)(bp + 32);
    float4_t c = {0.f, 0.f, 0.f, 0.f};
    c = __builtin_amdgcn_mfma_f32_16x16x32_f16(aq[0], b0, c, 0, 0, 0);
    c = __builtin_amdgcn_mfma_f32_16x16x32_f16(aq[1], b1, c, 0, 0, 0);
    float db = dec * fabsf((float)(j - 127));
#pragma unroll
    for (int i = 0; i < 4; i++) RelL[(quad * 4 + i) * RELS + j] = c[i] - db;
  }
  __syncthreads();

  // ---- scores in registers ----
  float4_t sreg[5];
#pragma unroll
  for (int tt = 0; tt < 5; tt++) { sreg[tt][0]=-1e30f; sreg[tt][1]=-1e30f; sreg[tt][2]=-1e30f; sreg[tt][3]=-1e30f; }

#pragma unroll
  for (int tt = 0; tt < 5; tt++) {
    int t = ts + tt;
    if (t < te) {
      int r0 = rlo + t * 16;
      const _Float16* kp = Kb + (size_t)(r0 + ln) * DK + quad * 8;
      half8_t b0 = *(const half8_t*)(kp);
      half8_t b1 = *(const half8_t*)(kp + 32);
      float4_t c = {0.f, 0.f, 0.f, 0.f};
      c = __builtin_amdgcn_mfma_f32_16x16x32_f16(aq[0], b0, c, 0, 0, 0);
      c = __builtin_amdgcn_mfma_f32_16x16x32_f16(aq[1], b1, c, 0, 0, 0);
      int r = r0 + ln;
#pragma unroll
      for (int i = 0; i < 4; i++) {
        int row = quad * 4 + i;
        int dd = r - (l0 + row);
        bool valid = (dd >= -127) && (dd <= 127);
        sreg[tt][i] = valid ? (c[i] + RelL[row * RELS + (dd + 127)]) : -1e30f;
      }
    }
  }

  // ---- softmax stats ----
  float mw[4] = {-1e30f, -1e30f, -1e30f, -1e30f};
#pragma unroll
  for (int tt = 0; tt < 5; tt++)
#pragma unroll
    for (int i = 0; i < 4; i++) mw[i] = fmaxf(mw[i], sreg[tt][i]);
#pragma unroll
  for (int off = 1; off < 16; off <<= 1)
#pragma unroll
    for (int i = 0; i < 4; i++) mw[i] = fmaxf(mw[i], __shfl_xor(mw[i], off, 64));

  float ew[4] = {0.f, 0.f, 0.f, 0.f};
#pragma unroll
  for (int tt = 0; tt < 5; tt++)
#pragma unroll
    for (int i = 0; i < 4; i++) {
      float e = (sreg[tt][i] > -1e29f) ? __expf(sreg[tt][i] - mw[i]) : 0.f;
      sreg[tt][i] = e;
      ew[i] += e;
    }
#pragma unroll
  for (int off = 1; off < 16; off <<= 1)
#pragma unroll
    for (int i = 0; i < 4; i++) ew[i] += __shfl_xor(ew[i], off, 64);

  if (ln == 0) {
#pragma unroll
    for (int i = 0; i < 4; i++) {
      statsM[wave][quad * 4 + i] = mw[i];
      statsZ[wave][quad * 4 + i] = ew[i];
    }
  }
  __syncthreads();

  float scale[4];
#pragma unroll
  for (int i = 0; i < 4; i++) {
    int row = quad * 4 + i;
    float mf = fmaxf(fmaxf(statsM[0][row], statsM[1][row]),
                     fmaxf(statsM[2][row], statsM[3][row]));
    float z = statsZ[0][row] * __expf(statsM[0][row] - mf)
            + statsZ[1][row] * __expf(statsM[1][row] - mf)
            + statsZ[2][row] * __expf(statsM[2][row] - mf)
            + statsZ[3][row] * __expf(statsM[3][row] - mf);
    scale[i] = __expf(mw[i] - mf) / z;
  }

  // ---- write normalized p to Pu and Pband ----
#pragma unroll
  for (int tt = 0; tt < 5; tt++) {
    int t = ts + tt;
    if (t < te) {
      int col = t * 16 + ln;
      int r = rlo + col;
#pragma unroll
      for (int i = 0; i < 4; i++) {
        int row = quad * 4 + i;
        _Float16 ph = (_Float16)(sreg[tt][i] * scale[i]);
        Pu[row * PUS + col] = ph;
        int dd = r - (l0 + row);
        if (dd >= -127 && dd <= 127) Pband[row * PBS + (dd + 127)] = ph;
      }
    }
  }
  __syncthreads();

  // ---- attn band store: dense, nontemporal ----
  {
    int row = tid >> 4;
    int lc = tid & 15;
    float* ar = arow + (size_t)row * S_LEN + rlo;
    const _Float16* pr = Pu + row * PUS;
    int W4 = W >> 2;
    for (int c4 = lc; c4 < W4; c4 += 16) {
      half4_t hp = *(const half4_t*)(pr + c4 * 4);
      float4_t f;
      f[0] = (float)hp[0]; f[1] = (float)hp[1];
      f[2] = (float)hp[2]; f[3] = (float)hp[3];
      __builtin_nontemporal_store(f, (float4_t*)(ar + c4 * 4));
    }
  }

  // ---- PV via 16x16x32 over 32-wide r chunks ----
  float4_t ctxa[4];
#pragma unroll
  for (int nt = 0; nt < 4; nt++) { ctxa[nt][0]=0.f; ctxa[nt][1]=0.f; ctxa[nt][2]=0.f; ctxa[nt][3]=0.f; }
  {
    int nC = (W + 31) >> 5;
    int cs = (wave * nC) >> 2, ce = ((wave + 1) * nC) >> 2;
    for (int cc2 = cs; cc2 < ce; cc2++) {
      half8_t a = *(const half8_t*)(Pu + ln * PUS + cc2 * 32 + quad * 8);
      int rb = rlo + cc2 * 32 + quad * 8;
#pragma unroll
      for (int nt = 0; nt < 4; nt++) {
        half8_t bv = *(const half8_t*)(Vb + (size_t)(nt * 16 + ln) * S_LEN + rb);
        ctxa[nt] = __builtin_amdgcn_mfma_f32_16x16x32_f16(a, bv, ctxa[nt], 0, 0, 0);
      }
    }
  }
#pragma unroll
  for (int nt = 0; nt < 4; nt++)
#pragma unroll
    for (int i = 0; i < 4; i++)
      atomicAdd(&ctxLds[(quad * 4 + i) * 64 + nt * 16 + ln], ctxa[nt][i]);
  __syncthreads();

  // ---- context += Pband @ rvT^T ----
  {
    float4_t rc = {0.f, 0.f, 0.f, 0.f};
#pragma unroll
    for (int cch = 0; cch < 8; cch++) {
      half8_t apb = *(const half8_t*)(Pband + ln * PBS + cch * 32 + quad * 8);
      half8_t bb  = *(const half8_t*)(rvT + (size_t)(wave * 16 + ln) * 256 + cch * 32 + quad * 8);
      rc = __builtin_amdgcn_mfma_f32_16x16x32_f16(apb, bb, rc, 0, 0, 0);
    }
#pragma unroll
    for (int i = 0; i < 4; i++)
      ctxLds[(quad * 4 + i) * 64 + wave * 16 + ln] += rc[i];
  }
  __syncthreads();

  // ---- ctx store (half4 per thread) ----
  {
    int l = tid >> 4, d4 = (tid & 15) * 4;
    const float* cs = ctxLds + l * 64 + d4;
    half4_t hv;
    hv[0] = (_Float16)cs[0]; hv[1] = (_Float16)cs[1];
    hv[2] = (_Float16)cs[2]; hv[3] = (_Float16)cs[3];
    *(half4_t*)(ctx + ((size_t)(b * S_LEN + l0 + l)) * DMODEL + h * DK + d4) = hv;
  }
}

// ---------------- launcher ----------------
extern "C" void kernel_launch(void* const* d_in, const int* in_sizes, int n_in,
                              void* d_out, int out_size, void* d_ws, size_t ws_size,
                              hipStream_t stream) {
  const float* q   = (const float*)d_in[0];
  const float* k   = (const float*)d_in[1];
  const float* v   = (const float*)d_in[2];
  const float* wq  = (const float*)d_in[3];
  const float* wk  = (const float*)d_in[4];
  const float* wv  = (const float*)d_in[5];
  const float* wo  = (const float*)d_in[6];
  const float* bo  = (const float*)d_in[7];
  const float* rk  = (const float*)d_in[8];
  const float* rv  = (const float*)d_in[9];
  const float* td  = (const float*)d_in[10];

  char* ws = (char*)d_ws;
  size_t off = 0;
  auto alloc = [&](size_t bytes) -> void* {
    void* p = ws + off;
    off += (bytes + 255) & ~(size_t)255;
    return p;
  };
  const size_t NTOK = (size_t)BATCH * S_LEN;
  _Float16* Xq  = (_Float16*)alloc(NTOK * DMODEL * 2);
  _Float16* Xk  = (_Float16*)alloc(NTOK * DMODEL * 2);
  _Float16* Xv  = (_Float16*)alloc(NTOK * DMODEL * 2);
  _Float16* Wqh = (_Float16*)alloc((size_t)DMODEL * DMODEL * 2);
  _Float16* Wkh = (_Float16*)alloc((size_t)DMODEL * DMODEL * 2);
  _Float16* Wvh = (_Float16*)alloc((size_t)DMODEL * DMODEL * 2);
  _Float16* Woh = (_Float16*)alloc((size_t)DMODEL * DMODEL * 2);
  _Float16* Qh  = (_Float16*)alloc(NTOK * DMODEL * 2);
  _Float16* Kh  = (_Float16*)alloc(NTOK * DMODEL * 2);
  _Float16* VtG = (_Float16*)alloc(NTOK * DMODEL * 2 + 256);
  _Float16* Ctx = (_Float16*)alloc(NTOK * DMODEL * 2);
  _Float16* Rkh = (_Float16*)alloc((size_t)257 * 64 * 2);
  _Float16* RvT = (_Float16*)alloc((size_t)64 * 256 * 2);

  CvtArgs ca;
  ca.r[0] = {q,  Xq,  (int)(NTOK * DMODEL / 4), 1.f};
  ca.r[1] = {k,  Xk,  (int)(NTOK * DMODEL / 4), 1.f};
  ca.r[2] = {v,  Xv,  (int)(NTOK * DMODEL / 4), 1.f};
  ca.r[3] = {wq, Wqh, DMODEL * DMODEL / 4, 0.125f};  // fold 1/sqrt(dk)
  ca.r[4] = {wk, Wkh, DMODEL * DMODEL / 4, 1.f};
  ca.r[5] = {wv, Wvh, DMODEL * DMODEL / 4, 1.f};
  ca.r[6] = {wo, Woh, DMODEL * DMODEL / 4, 1.f};
  ca.r[7] = {rk, Rkh, 257 * 64 / 4, 8.f};            // rel_k * 8 compensates
  cvt_all_kernel<<<dim3(512, 8), dim3(256), 0, stream>>>(ca);
  build_rvT_kernel<<<dim3(64), dim3(256), 0, stream>>>(rv, RvT);

  QkvArgs qa;
  qa.A[0] = Xq; qa.A[1] = Xk; qa.A[2] = Xv;
  qa.B[0] = Wqh; qa.B[1] = Wkh; qa.B[2] = Wvh;
  qa.dst[0] = Qh; qa.dst[1] = Kh; qa.dst[2] = VtG;
  gemm_qkv<<<dim3(64, 8, 3), dim3(256), 0, stream>>>(qa);

  float* attn_out = (float*)d_out + NTOK * DMODEL;
  attn4_kernel<<<dim3(BATCH * NHEADS * (S_LEN / 16)), dim3(256), 0, stream>>>(
      Qh, Kh, VtG, Rkh, RvT, td, attn_out, Ctx);

  gemm_out<<<dim3(64, 8), dim3(256), 0, stream>>>(Ctx, Woh, (float*)d_out, bo);
}

// Round 2
// 932.501 us; speedup vs baseline: 1.0011x; 1.0011x over previous
//
// TemporalAttention on MI355X (gfx950) — Round 5.
//  - gemm_core: BK 32 -> 64 (m97-proven config): 32 MFMA per barrier-pair
//    instead of 16, half the vmcnt(0)/lgkmcnt(0) barrier drains per block.
//    8-group XOR swizzle (g ^ (row&7)) on both stage-source and ds_read.
//  - attn4 unchanged this round (clean attribution of the GEMM delta).
//  - 5 dispatches: cvt_all, rvT, qkv gemm (z=3), attn, out gemm.

#include <hip/hip_runtime.h>
#include <cstdint>
#include <cstddef>

#define S_LEN 1024
#define DMODEL 1024
#define NHEADS 16
#define DK 64
#define BATCH 8
#define PUS 296    // Pu row stride (halves)
#define PBS 272    // Pband row stride (halves)
#define RELS 257   // RelL row stride (floats)

using half8_t  = __attribute__((ext_vector_type(8))) _Float16;
using half4_t  = __attribute__((ext_vector_type(4))) _Float16;
using float4_t = __attribute__((ext_vector_type(4))) float;

__device__ __forceinline__ void async16(const void* g, void* l) {
  __builtin_amdgcn_global_load_lds(
      (const __attribute__((address_space(1))) unsigned int*)g,
      (__attribute__((address_space(3))) unsigned int*)l, 16, 0, 0);
}

// ---------------- merged fp32 -> fp16 convert (8 regions) ----------------
struct CvtRegion { const float* src; _Float16* dst; int n4; float scale; };
struct CvtArgs { CvtRegion r[8]; };

__global__ __launch_bounds__(256) void cvt_all_kernel(CvtArgs a) {
  CvtRegion reg = a.r[blockIdx.y];
  const int stride = gridDim.x * 256;
  for (int i = blockIdx.x * 256 + threadIdx.x; i < reg.n4; i += stride) {
    float4_t f = ((const float4_t*)reg.src)[i];
    half4_t h;
    h[0] = (_Float16)(f[0] * reg.scale); h[1] = (_Float16)(f[1] * reg.scale);
    h[2] = (_Float16)(f[2] * reg.scale); h[3] = (_Float16)(f[3] * reg.scale);
    ((half4_t*)reg.dst)[i] = h;
  }
}

// rvT[d][j] = rel_v[j+1][d] for j in [0,255), col 255 = 0.
__global__ void build_rvT_kernel(const float* __restrict__ relv, _Float16* __restrict__ rvT) {
  int d = blockIdx.x;
  int j = threadIdx.x;
  rvT[d * 256 + j] = (j < 255) ? (_Float16)relv[(size_t)(j + 1) * DK + d] : (_Float16)0.f;
}

// ---------------- GEMM core: acc = A[128,K] * B[128,K]^T tile, BK=64 ----------------
__device__ __forceinline__ void gemm_core(
    const _Float16* __restrict__ A, const _Float16* __restrict__ B,
    _Float16* smem, float4_t acc[4][4], int m0, int n0,
    int wave, int lane, int quad, int ln, int wm, int wn)
{
  _Float16* As = smem;            // 128 rows x 64 halves (16 KB)
  _Float16* Bs = smem + 8192;     // 128 rows x 64 halves (16 KB)
#pragma unroll
  for (int i = 0; i < 4; i++)
#pragma unroll
    for (int j = 0; j < 4; j++) { acc[i][j][0]=0.f; acc[i][j][1]=0.f; acc[i][j][2]=0.f; acc[i][j][3]=0.f; }

  for (int k0 = 0; k0 < 1024; k0 += 64) {
    // stage A/B 128x64 tiles: 1024 slots of 16B each, 4 per thread per matrix.
    // LDS dest linear in slot (wave-uniform base + lane*16B); global source
    // pre-swizzled: column-group g ^ (row & 7)  (same involution on read).
#pragma unroll
    for (int q = 0; q < 4; q++) {
      int slot = q * 256 + wave * 64 + lane;
      int m = slot >> 3, g = slot & 7;
      int gg = g ^ (m & 7);
      async16(A + (size_t)(m0 + m) * 1024 + k0 + gg * 8,
              As + (size_t)(q * 256 + wave * 64) * 8);
      async16(B + (size_t)(n0 + m) * 1024 + k0 + gg * 8,
              Bs + (size_t)(q * 256 + wave * 64) * 8);
    }
    __syncthreads();
    half8_t af[4][2], bf[4][2];
#pragma unroll
    for (int t = 0; t < 4; t++) {
      int mm = wm + t * 16 + ln;
      int nn = wn + t * 16 + ln;
#pragma unroll
      for (int kk = 0; kk < 2; kk++) {
        af[t][kk] = *(const half8_t*)(As + mm * 64 + (((kk * 4 + quad) ^ (mm & 7)) * 8));
        bf[t][kk] = *(const half8_t*)(Bs + nn * 64 + (((kk * 4 + quad) ^ (nn & 7)) * 8));
      }
    }
#pragma unroll
    for (int i = 0; i < 4; i++)
#pragma unroll
      for (int j = 0; j < 4; j++) {
        acc[i][j] = __builtin_amdgcn_mfma_f32_16x16x32_f16(af[i][0], bf[j][0], acc[i][j], 0, 0, 0);
        acc[i][j] = __builtin_amdgcn_mfma_f32_16x16x32_f16(af[i][1], bf[j][1], acc[i][j], 0, 0, 0);
      }
    __syncthreads();
  }
}

// ---------------- fused QKV projection (grid.z = 0:Q 1:K 2:V) ----------------
struct QkvArgs {
  const _Float16* A[3];
  const _Float16* B[3];
  _Float16* dst[3];
};

__global__ __launch_bounds__(256) void gemm_qkv(QkvArgs qa) {
  __shared__ _Float16 smem[16384];
  const int tid = threadIdx.x;
  const int wave = tid >> 6, lane = tid & 63;
  const int quad = lane >> 4, ln = lane & 15;
  const int m0 = blockIdx.x * 128, n0 = blockIdx.y * 128;
  const int wm = (wave >> 1) * 64, wn = (wave & 1) * 64;
  const int z = blockIdx.z;

  float4_t acc[4][4];
  gemm_core(qa.A[z], qa.B[z], smem, acc, m0, n0, wave, lane, quad, ln, wm, wn);

  _Float16* o = qa.dst[z];
  if (z < 2) {
    // [B,H,S,dk] via LDS transpose, coalesced 16B stores. (Q pre-scaled via w_q)
    _Float16* T = smem + wave * 1152;               // 16 x 72
    size_t headoff = ((size_t)((n0 + wn) >> 6)) << 16;
#pragma unroll
    for (int i = 0; i < 4; i++) {
#pragma unroll
      for (int j = 0; j < 4; j++)
#pragma unroll
        for (int r = 0; r < 4; r++)
          T[(quad * 4 + r) * 72 + j * 16 + ln] = (_Float16)acc[i][j][r];
      int mbase = m0 + wm + i * 16;
#pragma unroll
      for (int p = 0; p < 2; p++) {
        int row = p * 8 + (lane >> 3);
        int cc = (lane & 7) * 8;
        half8_t hv = *(const half8_t*)(T + row * 72 + cc);
        int token = mbase + row;
        size_t idx = ((size_t)(token >> 10) << 20) | headoff
                   | ((size_t)(token & 1023) << 6) | (size_t)cc;
        *(half8_t*)(o + idx) = hv;
      }
    }
  } else {
    // V^T per head [B,H,dk,S]: per j-slice LDS transpose -> 128B-row stores.
    _Float16* T = smem + wave * 1160;               // 16 (d) x 72 (token+pad)
    const int tok0 = m0 + wm;                       // 64 tokens, same batch
    const size_t base = ((size_t)(tok0 >> 10) << 20)
                      | (((size_t)((n0 + wn) >> 6)) << 16)
                      | (size_t)(tok0 & 1023);
#pragma unroll
    for (int j = 0; j < 4; j++) {
#pragma unroll
      for (int i = 0; i < 4; i++)
#pragma unroll
        for (int r = 0; r < 4; r++)
          T[ln * 72 + i * 16 + quad * 4 + r] = (_Float16)acc[i][j][r];
#pragma unroll
      for (int p = 0; p < 2; p++) {
        int drow = p * 8 + (lane >> 3);
        int cc = (lane & 7) * 8;
        half8_t hv = *(const half8_t*)(T + drow * 72 + cc);
        size_t idx = base + (((size_t)(j * 16 + drow)) << 10) + (size_t)cc;
        *(half8_t*)(o + idx) = hv;
      }
    }
  }
}

// ---------------- output projection (fp32 + bias) ----------------
__global__ __launch_bounds__(256) void gemm_out(
    const _Float16* __restrict__ A, const _Float16* __restrict__ B,
    float* __restrict__ o, const float* __restrict__ bias)
{
  __shared__ _Float16 smem[16384];
  const int tid = threadIdx.x;
  const int wave = tid >> 6, lane = tid & 63;
  const int quad = lane >> 4, ln = lane & 15;
  const int m0 = blockIdx.x * 128, n0 = blockIdx.y * 128;
  const int wm = (wave >> 1) * 64, wn = (wave & 1) * 64;

  float4_t acc[4][4];
  gemm_core(A, B, smem, acc, m0, n0, wave, lane, quad, ln, wm, wn);

#pragma unroll
  for (int i = 0; i < 4; i++)
#pragma unroll
    for (int j = 0; j < 4; j++) {
      int nn = n0 + wn + j * 16 + ln;
      float bb = bias[nn];
#pragma unroll
      for (int r = 0; r < 4; r++) {
        int mm = m0 + wm + i * 16 + quad * 4 + r;
        o[(size_t)mm * 1024 + nn] = acc[i][j][r] + bb;
      }
    }
}

// ---------------- fused windowed attention ----------------
__global__ __launch_bounds__(256, 4) void attn4_kernel(
    const _Float16* __restrict__ Qh, const _Float16* __restrict__ Kh,
    const _Float16* __restrict__ VtG, const _Float16* __restrict__ relk,
    const _Float16* __restrict__ rvT, const float* __restrict__ decay,
    float* __restrict__ attn_out, _Float16* __restrict__ ctx)
{
  __shared__ float    RelL[16 * RELS];
  __shared__ _Float16 Pu[16 * PUS];
  __shared__ _Float16 Pband[16 * PBS];
  __shared__ float    ctxLds[16 * 64];
  __shared__ float    statsM[4][16];
  __shared__ float    statsZ[4][16];

  const int tid = threadIdx.x;
  const int wave = tid >> 6, lane = tid & 63;
  const int quad = lane >> 4, ln = lane & 15;
  const int bid = blockIdx.x;
  const int b = bid >> 10, h = (bid >> 6) & 15, lt = bid & 63;
  const int l0 = lt * 16;
  const int bh = b * NHEADS + h;
  const _Float16* Qb = Qh + ((size_t)bh << 16);
  const _Float16* Kb = Kh + ((size_t)bh << 16);
  const _Float16* Vb = VtG + ((size_t)bh << 16);
  float* arow = attn_out + ((size_t)bh << 20) + (size_t)l0 * S_LEN;
  const float dec = decay[h];

  const int rlo = (l0 > 127) ? ((l0 - 127) & ~15) : 0;
  int rhi = (l0 + 158) & ~15;
  if (rhi > S_LEN) rhi = S_LEN;
  const int W = rhi - rlo;
  const int nT = W >> 4;
  const int ts = (wave * nT) >> 2;
  const int te = ((wave + 1) * nT) >> 2;

  // ---- zero fills (division-free: row-outer) ----
  const float4_t fz = {0.f, 0.f, 0.f, 0.f};
  {
    int w4l = rlo >> 2;
    int w4r = (S_LEN - rhi) >> 2;
#pragma unroll 1
    for (int row = 0; row < 16; row++) {
      float* ar = arow + (size_t)row * S_LEN;
      for (int c4 = tid; c4 < w4l; c4 += 256)
        __builtin_nontemporal_store(fz, (float4_t*)(ar + c4 * 4));
      float* ar2 = ar + rhi;
      for (int c4 = tid; c4 < w4r; c4 += 256)
        __builtin_nontemporal_store(fz, (float4_t*)(ar2 + c4 * 4));
    }
  }
  ((float4_t*)ctxLds)[tid] = fz;
  {
    const half8_t hz = {};
    for (int i = tid; i < 16 * PBS / 8; i += 256) ((half8_t*)Pband)[i] = hz;
    for (int i = tid; i < 16 * PUS / 8; i += 256) ((half8_t*)Pu)[i] = hz;
  }

  // ---- Q fragments (pre-scaled by 1/8 via w_q) ----
  half8_t aq[2];
  {
    const _Float16* qp = Qb + (size_t)(l0 + ln) * DK + quad * 8;
    aq[0] = *(const half8_t*)(qp);
    aq[1] = *(const half8_t*)(qp + 32);
  }

  // ---- RelL[l][j] = (Q/8).(8*rel_k[j+1]) - dec*|j-127| ----
#pragma unroll
  for (int s = 0; s < 4; s++) {
    int nt = wave * 4 + s;
    int j = nt * 16 + ln;
    const _Float16* bp = relk + (size_t)(j + 1) * DK + quad * 8;
    half8_t b0 = *(const half8_t*)bp;
    half8_t b1 = *(const half8_t*)(bp + 32);
    float4_t c = {0.f, 0.f, 0.f, 0.f};
    c = __builtin_amdgcn_mfma_f32_16x16x32_f16(aq[0], b0, c, 0, 0, 0);
    c = __builtin_amdgcn_mfma_f32_16x16x32_f16(aq[1], b1, c, 0, 0, 0);
    float db = dec * fabsf((float)(j - 127));
#pragma unroll
    for (int i = 0; i < 4; i++) RelL[(quad * 4 + i) * RELS + j] = c[i] - db;
  }
  __syncthreads();

  // ---- scores in registers ----
  float4_t sreg[5];
#pragma unroll
  for (int tt = 0; tt < 5; tt++) { sreg[tt][0]=-1e30f; sreg[tt][1]=-1e30f; sreg[tt][2]=-1e30f; sreg[tt][3]=-1e30f; }

#pragma unroll
  for (int tt = 0; tt < 5; tt++) {
    int t = ts + tt;
    if (t < te) {
      int r0 = rlo + t * 16;
      const _Float16* kp = Kb + (size_t)(r0 + ln) * DK + quad * 8;
      half8_t b0 = *(const half8_t*)(kp);
      half8_t b1 = *(const half8_t*)(kp + 32);
      float4_t c = {0.f, 0.f, 0.f, 0.f};
      c = __builtin_amdgcn_mfma_f32_16x16x32_f16(aq[0], b0, c, 0, 0, 0);
      c = __builtin_amdgcn_mfma_f32_16x16x32_f16(aq[1], b1, c, 0, 0, 0);
      int r = r0 + ln;
#pragma unroll
      for (int i = 0; i < 4; i++) {
        int row = quad * 4 + i;
        int dd = r - (l0 + row);
        bool valid = (dd >= -127) && (dd <= 127);
        sreg[tt][i] = valid ? (c[i] + RelL[row * RELS + (dd + 127)]) : -1e30f;
      }
    }
  }

  // ---- softmax stats ----
  float mw[4] = {-1e30f, -1e30f, -1e30f, -1e30f};
#pragma unroll
  for (int tt = 0; tt < 5; tt++)
#pragma unroll
    for (int i = 0; i < 4; i++) mw[i] = fmaxf(mw[i], sreg[tt][i]);
#pragma unroll
  for (int off = 1; off < 16; off <<= 1)
#pragma unroll
    for (int i = 0; i < 4; i++) mw[i] = fmaxf(mw[i], __shfl_xor(mw[i], off, 64));

  float ew[4] = {0.f, 0.f, 0.f, 0.f};
#pragma unroll
  for (int tt = 0; tt < 5; tt++)
#pragma unroll
    for (int i = 0; i < 4; i++) {
      float e = (sreg[tt][i] > -1e29f) ? __expf(sreg[tt][i] - mw[i]) : 0.f;
      sreg[tt][i] = e;
      ew[i] += e;
    }
#pragma unroll
  for (int off = 1; off < 16; off <<= 1)
#pragma unroll
    for (int i = 0; i < 4; i++) ew[i] += __shfl_xor(ew[i], off, 64);

  if (ln == 0) {
#pragma unroll
    for (int i = 0; i < 4; i++) {
      statsM[wave][quad * 4 + i] = mw[i];
      statsZ[wave][quad * 4 + i] = ew[i];
    }
  }
  __syncthreads();

  float scale[4];
#pragma unroll
  for (int i = 0; i < 4; i++) {
    int row = quad * 4 + i;
    float mf = fmaxf(fmaxf(statsM[0][row], statsM[1][row]),
                     fmaxf(statsM[2][row], statsM[3][row]));
    float z = statsZ[0][row] * __expf(statsM[0][row] - mf)
            + statsZ[1][row] * __expf(statsM[1][row] - mf)
            + statsZ[2][row] * __expf(statsM[2][row] - mf)
            + statsZ[3][row] * __expf(statsM[3][row] - mf);
    scale[i] = __expf(mw[i] - mf) / z;
  }

  // ---- write normalized p to Pu and Pband ----
#pragma unroll
  for (int tt = 0; tt < 5; tt++) {
    int t = ts + tt;
    if (t < te) {
      int col = t * 16 + ln;
      int r = rlo + col;
#pragma unroll
      for (int i = 0; i < 4; i++) {
        int row = quad * 4 + i;
        _Float16 ph = (_Float16)(sreg[tt][i] * scale[i]);
        Pu[row * PUS + col] = ph;
        int dd = r - (l0 + row);
        if (dd >= -127 && dd <= 127) Pband[row * PBS + (dd + 127)] = ph;
      }
    }
  }
  __syncthreads();

  // ---- attn band store: dense, nontemporal ----
  {
    int row = tid >> 4;
    int lc = tid & 15;
    float* ar = arow + (size_t)row * S_LEN + rlo;
    const _Float16* pr = Pu + row * PUS;
    int W4 = W >> 2;
    for (int c4 = lc; c4 < W4; c4 += 16) {
      half4_t hp = *(const half4_t*)(pr + c4 * 4);
      float4_t f;
      f[0] = (float)hp[0]; f[1] = (float)hp[1];
      f[2] = (float)hp[2]; f[3] = (float)hp[3];
      __builtin_nontemporal_store(f, (float4_t*)(ar + c4 * 4));
    }
  }

  // ---- PV via 16x16x32 over 32-wide r chunks ----
  float4_t ctxa[4];
#pragma unroll
  for (int nt = 0; nt < 4; nt++) { ctxa[nt][0]=0.f; ctxa[nt][1]=0.f; ctxa[nt][2]=0.f; ctxa[nt][3]=0.f; }
  {
    int nC = (W + 31) >> 5;
    int cs = (wave * nC) >> 2, ce = ((wave + 1) * nC) >> 2;
    for (int cc2 = cs; cc2 < ce; cc2++) {
      half8_t a = *(const half8_t*)(Pu + ln * PUS + cc2 * 32 + quad * 8);
      int rb = rlo + cc2 * 32 + quad * 8;
#pragma unroll
      for (int nt = 0; nt < 4; nt++) {
        half8_t bv = *(const half8_t*)(Vb + (size_t)(nt * 16 + ln) * S_LEN + rb);
        ctxa[nt] = __builtin_amdgcn_mfma_f32_16x16x32_f16(a, bv, ctxa[nt], 0, 0, 0);
      }
    }
  }
#pragma unroll
  for (int nt = 0; nt < 4; nt++)
#pragma unroll
    for (int i = 0; i < 4; i++)
      atomicAdd(&ctxLds[(quad * 4 + i) * 64 + nt * 16 + ln], ctxa[nt][i]);
  __syncthreads();

  // ---- context += Pband @ rvT^T ----
  {
    float4_t rc = {0.f, 0.f, 0.f, 0.f};
#pragma unroll
    for (int cch = 0; cch < 8; cch++) {
      half8_t apb = *(const half8_t*)(Pband + ln * PBS + cch * 32 + quad * 8);
      half8_t bb  = *(const half8_t*)(rvT + (size_t)(wave * 16 + ln) * 256 + cch * 32 + quad * 8);
      rc = __builtin_amdgcn_mfma_f32_16x16x32_f16(apb, bb, rc, 0, 0, 0);
    }
#pragma unroll
    for (int i = 0; i < 4; i++)
      ctxLds[(quad * 4 + i) * 64 + wave * 16 + ln] += rc[i];
  }
  __syncthreads();

  // ---- ctx store (half4 per thread) ----
  {
    int l = tid >> 4, d4 = (tid & 15) * 4;
    const float* cs = ctxLds + l * 64 + d4;
    half4_t hv;
    hv[0] = (_Float16)cs[0]; hv[1] = (_Float16)cs[1];
    hv[2] = (_Float16)cs[2]; hv[3] = (_Float16)cs[3];
    *(half4_t*)(ctx + ((size_t)(b * S_LEN + l0 + l)) * DMODEL + h * DK + d4) = hv;
  }
}

// ---------------- launcher ----------------
extern "C" void kernel_launch(void* const* d_in, const int* in_sizes, int n_in,
                              void* d_out, int out_size, void* d_ws, size_t ws_size,
                              hipStream_t stream) {
  const float* q   = (const float*)d_in[0];
  const float* k   = (const float*)d_in[1];
  const float* v   = (const float*)d_in[2];
  const float* wq  = (const float*)d_in[3];
  const float* wk  = (const float*)d_in[4];
  const float* wv  = (const float*)d_in[5];
  const float* wo  = (const float*)d_in[6];
  const float* bo  = (const float*)d_in[7];
  const float* rk  = (const float*)d_in[8];
  const float* rv  = (const float*)d_in[9];
  const float* td  = (const float*)d_in[10];

  char* ws = (char*)d_ws;
  size_t off = 0;
  auto alloc = [&](size_t bytes) -> void* {
    void* p = ws + off;
    off += (bytes + 255) & ~(size_t)255;
    return p;
  };
  const size_t NTOK = (size_t)BATCH * S_LEN;
  _Float16* Xq  = (_Float16*)alloc(NTOK * DMODEL * 2);
  _Float16* Xk  = (_Float16*)alloc(NTOK * DMODEL * 2);
  _Float16* Xv  = (_Float16*)alloc(NTOK * DMODEL * 2);
  _Float16* Wqh = (_Float16*)alloc((size_t)DMODEL * DMODEL * 2);
  _Float16* Wkh = (_Float16*)alloc((size_t)DMODEL * DMODEL * 2);
  _Float16* Wvh = (_Float16*)alloc((size_t)DMODEL * DMODEL * 2);
  _Float16* Woh = (_Float16*)alloc((size_t)DMODEL * DMODEL * 2);
  _Float16* Qh  = (_Float16*)alloc(NTOK * DMODEL * 2);
  _Float16* Kh  = (_Float16*)alloc(NTOK * DMODEL * 2);
  _Float16* VtG = (_Float16*)alloc(NTOK * DMODEL * 2 + 256);
  _Float16* Ctx = (_Float16*)alloc(NTOK * DMODEL * 2);
  _Float16* Rkh = (_Float16*)alloc((size_t)257 * 64 * 2);
  _Float16* RvT = (_Float16*)alloc((size_t)64 * 256 * 2);

  CvtArgs ca;
  ca.r[0] = {q,  Xq,  (int)(NTOK * DMODEL / 4), 1.f};
  ca.r[1] = {k,  Xk,  (int)(NTOK * DMODEL / 4), 1.f};
  ca.r[2] = {v,  Xv,  (int)(NTOK * DMODEL / 4), 1.f};
  ca.r[3] = {wq, Wqh, DMODEL * DMODEL / 4, 0.125f};  // fold 1/sqrt(dk)
  ca.r[4] = {wk, Wkh, DMODEL * DMODEL / 4, 1.f};
  ca.r[5] = {wv, Wvh, DMODEL * DMODEL / 4, 1.f};
  ca.r[6] = {wo, Woh, DMODEL * DMODEL / 4, 1.f};
  ca.r[7] = {rk, Rkh, 257 * 64 / 4, 8.f};            // rel_k * 8 compensates
  cvt_all_kernel<<<dim3(512, 8), dim3(256), 0, stream>>>(ca);
  build_rvT_kernel<<<dim3(64), dim3(256), 0, stream>>>(rv, RvT);

  QkvArgs qa;
  qa.A[0] = Xq; qa.A[1] = Xk; qa.A[2] = Xv;
  qa.B[0] = Wqh; qa.B[1] = Wkh; qa.B[2] = Wvh;
  qa.dst[0] = Qh; qa.dst[1] = Kh; qa.dst[2] = VtG;
  gemm_qkv<<<dim3(64, 8, 3), dim3(256), 0, stream>>>(qa);

  float* attn_out = (float*)d_out + NTOK * DMODEL;
  attn4_kernel<<<dim3(BATCH * NHEADS * (S_LEN / 16)), dim3(256), 0, stream>>>(
      Qh, Kh, VtG, Rkh, RvT, td, attn_out, Ctx);

  gemm_out<<<dim3(64, 8), dim3(256), 0, stream>>>(Ctx, Woh, (float*)d_out, bo);
}

// Round 3
// 793.765 us; speedup vs baseline: 1.1761x; 1.1748x over previous
//
// TemporalAttention on MI355X (gfx950) — Round 6.
//  - attn4: XCD-chunked block swizzle (T1: consecutive lt share K/V window ->
//    same XCD L2; 8192%8==0 so simple bijective form).
//  - attn4: PV reduction via per-wave LDS slabs (reuses dead RelL scratch,
//    stride 68 = 2-way bank alias = free) instead of 4096 contended atomicAdds.
//  - attn4: rel_v GEMM folded into PV phase (rc added in-register into
//    ctxa[wave] with static indexing); 5 barriers -> 4; ctxLds eliminated.
//  - GEMMs unchanged from Round 5 (BK=64) for clean attribution.

#include <hip/hip_runtime.h>
#include <cstdint>
#include <cstddef>

#define S_LEN 1024
#define DMODEL 1024
#define NHEADS 16
#define DK 64
#define BATCH 8
#define PUS 296    // Pu row stride (halves)
#define PBS 272    // Pband row stride (halves)
#define RELS 257   // RelL row stride (floats)
#define SLABS 68   // ctx slab row stride (floats): 2-way bank alias (free)

using half8_t  = __attribute__((ext_vector_type(8))) _Float16;
using half4_t  = __attribute__((ext_vector_type(4))) _Float16;
using float4_t = __attribute__((ext_vector_type(4))) float;

__device__ __forceinline__ void async16(const void* g, void* l) {
  __builtin_amdgcn_global_load_lds(
      (const __attribute__((address_space(1))) unsigned int*)g,
      (__attribute__((address_space(3))) unsigned int*)l, 16, 0, 0);
}

// ---------------- merged fp32 -> fp16 convert (8 regions) ----------------
struct CvtRegion { const float* src; _Float16* dst; int n4; float scale; };
struct CvtArgs { CvtRegion r[8]; };

__global__ __launch_bounds__(256) void cvt_all_kernel(CvtArgs a) {
  CvtRegion reg = a.r[blockIdx.y];
  const int stride = gridDim.x * 256;
  for (int i = blockIdx.x * 256 + threadIdx.x; i < reg.n4; i += stride) {
    float4_t f = ((const float4_t*)reg.src)[i];
    half4_t h;
    h[0] = (_Float16)(f[0] * reg.scale); h[1] = (_Float16)(f[1] * reg.scale);
    h[2] = (_Float16)(f[2] * reg.scale); h[3] = (_Float16)(f[3] * reg.scale);
    ((half4_t*)reg.dst)[i] = h;
  }
}

// rvT[d][j] = rel_v[j+1][d] for j in [0,255), col 255 = 0.
__global__ void build_rvT_kernel(const float* __restrict__ relv, _Float16* __restrict__ rvT) {
  int d = blockIdx.x;
  int j = threadIdx.x;
  rvT[d * 256 + j] = (j < 255) ? (_Float16)relv[(size_t)(j + 1) * DK + d] : (_Float16)0.f;
}

// ---------------- GEMM core: acc = A[128,K] * B[128,K]^T tile, BK=64 ----------------
__device__ __forceinline__ void gemm_core(
    const _Float16* __restrict__ A, const _Float16* __restrict__ B,
    _Float16* smem, float4_t acc[4][4], int m0, int n0,
    int wave, int lane, int quad, int ln, int wm, int wn)
{
  _Float16* As = smem;            // 128 rows x 64 halves (16 KB)
  _Float16* Bs = smem + 8192;     // 128 rows x 64 halves (16 KB)
#pragma unroll
  for (int i = 0; i < 4; i++)
#pragma unroll
    for (int j = 0; j < 4; j++) { acc[i][j][0]=0.f; acc[i][j][1]=0.f; acc[i][j][2]=0.f; acc[i][j][3]=0.f; }

  for (int k0 = 0; k0 < 1024; k0 += 64) {
#pragma unroll
    for (int q = 0; q < 4; q++) {
      int slot = q * 256 + wave * 64 + lane;
      int m = slot >> 3, g = slot & 7;
      int gg = g ^ (m & 7);
      async16(A + (size_t)(m0 + m) * 1024 + k0 + gg * 8,
              As + (size_t)(q * 256 + wave * 64) * 8);
      async16(B + (size_t)(n0 + m) * 1024 + k0 + gg * 8,
              Bs + (size_t)(q * 256 + wave * 64) * 8);
    }
    __syncthreads();
    half8_t af[4][2], bf[4][2];
#pragma unroll
    for (int t = 0; t < 4; t++) {
      int mm = wm + t * 16 + ln;
      int nn = wn + t * 16 + ln;
#pragma unroll
      for (int kk = 0; kk < 2; kk++) {
        af[t][kk] = *(const half8_t*)(As + mm * 64 + (((kk * 4 + quad) ^ (mm & 7)) * 8));
        bf[t][kk] = *(const half8_t*)(Bs + nn * 64 + (((kk * 4 + quad) ^ (nn & 7)) * 8));
      }
    }
#pragma unroll
    for (int i = 0; i < 4; i++)
#pragma unroll
      for (int j = 0; j < 4; j++) {
        acc[i][j] = __builtin_amdgcn_mfma_f32_16x16x32_f16(af[i][0], bf[j][0], acc[i][j], 0, 0, 0);
        acc[i][j] = __builtin_amdgcn_mfma_f32_16x16x32_f16(af[i][1], bf[j][1], acc[i][j], 0, 0, 0);
      }
    __syncthreads();
  }
}

// ---------------- fused QKV projection (grid.z = 0:Q 1:K 2:V) ----------------
struct QkvArgs {
  const _Float16* A[3];
  const _Float16* B[3];
  _Float16* dst[3];
};

__global__ __launch_bounds__(256) void gemm_qkv(QkvArgs qa) {
  __shared__ _Float16 smem[16384];
  const int tid = threadIdx.x;
  const int wave = tid >> 6, lane = tid & 63;
  const int quad = lane >> 4, ln = lane & 15;
  const int m0 = blockIdx.x * 128, n0 = blockIdx.y * 128;
  const int wm = (wave >> 1) * 64, wn = (wave & 1) * 64;
  const int z = blockIdx.z;

  float4_t acc[4][4];
  gemm_core(qa.A[z], qa.B[z], smem, acc, m0, n0, wave, lane, quad, ln, wm, wn);

  _Float16* o = qa.dst[z];
  if (z < 2) {
    // [B,H,S,dk] via LDS transpose, coalesced 16B stores. (Q pre-scaled via w_q)
    _Float16* T = smem + wave * 1152;               // 16 x 72
    size_t headoff = ((size_t)((n0 + wn) >> 6)) << 16;
#pragma unroll
    for (int i = 0; i < 4; i++) {
#pragma unroll
      for (int j = 0; j < 4; j++)
#pragma unroll
        for (int r = 0; r < 4; r++)
          T[(quad * 4 + r) * 72 + j * 16 + ln] = (_Float16)acc[i][j][r];
      int mbase = m0 + wm + i * 16;
#pragma unroll
      for (int p = 0; p < 2; p++) {
        int row = p * 8 + (lane >> 3);
        int cc = (lane & 7) * 8;
        half8_t hv = *(const half8_t*)(T + row * 72 + cc);
        int token = mbase + row;
        size_t idx = ((size_t)(token >> 10) << 20) | headoff
                   | ((size_t)(token & 1023) << 6) | (size_t)cc;
        *(half8_t*)(o + idx) = hv;
      }
    }
  } else {
    // V^T per head [B,H,dk,S]: per j-slice LDS transpose -> 128B-row stores.
    _Float16* T = smem + wave * 1160;               // 16 (d) x 72 (token+pad)
    const int tok0 = m0 + wm;                       // 64 tokens, same batch
    const size_t base = ((size_t)(tok0 >> 10) << 20)
                      | (((size_t)((n0 + wn) >> 6)) << 16)
                      | (size_t)(tok0 & 1023);
#pragma unroll
    for (int j = 0; j < 4; j++) {
#pragma unroll
      for (int i = 0; i < 4; i++)
#pragma unroll
        for (int r = 0; r < 4; r++)
          T[ln * 72 + i * 16 + quad * 4 + r] = (_Float16)acc[i][j][r];
#pragma unroll
      for (int p = 0; p < 2; p++) {
        int drow = p * 8 + (lane >> 3);
        int cc = (lane & 7) * 8;
        half8_t hv = *(const half8_t*)(T + drow * 72 + cc);
        size_t idx = base + (((size_t)(j * 16 + drow)) << 10) + (size_t)cc;
        *(half8_t*)(o + idx) = hv;
      }
    }
  }
}

// ---------------- output projection (fp32 + bias) ----------------
__global__ __launch_bounds__(256) void gemm_out(
    const _Float16* __restrict__ A, const _Float16* __restrict__ B,
    float* __restrict__ o, const float* __restrict__ bias)
{
  __shared__ _Float16 smem[16384];
  const int tid = threadIdx.x;
  const int wave = tid >> 6, lane = tid & 63;
  const int quad = lane >> 4, ln = lane & 15;
  const int m0 = blockIdx.x * 128, n0 = blockIdx.y * 128;
  const int wm = (wave >> 1) * 64, wn = (wave & 1) * 64;

  float4_t acc[4][4];
  gemm_core(A, B, smem, acc, m0, n0, wave, lane, quad, ln, wm, wn);

#pragma unroll
  for (int i = 0; i < 4; i++)
#pragma unroll
    for (int j = 0; j < 4; j++) {
      int nn = n0 + wn + j * 16 + ln;
      float bb = bias[nn];
#pragma unroll
      for (int r = 0; r < 4; r++) {
        int mm = m0 + wm + i * 16 + quad * 4 + r;
        o[(size_t)mm * 1024 + nn] = acc[i][j][r] + bb;
      }
    }
}

// ---------------- fused windowed attention ----------------
__global__ __launch_bounds__(256, 4) void attn4_kernel(
    const _Float16* __restrict__ Qh, const _Float16* __restrict__ Kh,
    const _Float16* __restrict__ VtG, const _Float16* __restrict__ relk,
    const _Float16* __restrict__ rvT, const float* __restrict__ decay,
    float* __restrict__ attn_out, _Float16* __restrict__ ctx)
{
  // scratch: phase 1 = RelL[16][257] f32 (16448 B); phase 2 = ctx slabs
  // [4][16][SLABS] f32 (17408 B). RelL dead after the scores phase (barrier
  // separated), so the region is reused.
  __shared__ float    scratch[4 * 16 * SLABS];
  __shared__ _Float16 Pu[16 * PUS];
  __shared__ _Float16 Pband[16 * PBS];
  __shared__ float    statsM[4][16];
  __shared__ float    statsZ[4][16];

  const int tid = threadIdx.x;
  const int wave = tid >> 6, lane = tid & 63;
  const int quad = lane >> 4, ln = lane & 15;
  // XCD-chunked bijective swizzle: HW round-robins blockIdx.x across 8 XCDs;
  // remap so logical-consecutive lt (shared K/V window) land on one XCD's L2.
  const int hw = blockIdx.x;
  const int bid = ((hw & 7) << 10) | (hw >> 3);
  const int b = bid >> 10, h = (bid >> 6) & 15, lt = bid & 63;
  const int l0 = lt * 16;
  const int bh = b * NHEADS + h;
  const _Float16* Qb = Qh + ((size_t)bh << 16);
  const _Float16* Kb = Kh + ((size_t)bh << 16);
  const _Float16* Vb = VtG + ((size_t)bh << 16);
  float* arow = attn_out + ((size_t)bh << 20) + (size_t)l0 * S_LEN;
  const float dec = decay[h];

  const int rlo = (l0 > 127) ? ((l0 - 127) & ~15) : 0;
  int rhi = (l0 + 158) & ~15;
  if (rhi > S_LEN) rhi = S_LEN;
  const int W = rhi - rlo;
  const int nT = W >> 4;
  const int ts = (wave * nT) >> 2;
  const int te = ((wave + 1) * nT) >> 2;

  // ---- zero fills (division-free: row-outer) ----
  const float4_t fz = {0.f, 0.f, 0.f, 0.f};
  {
    int w4l = rlo >> 2;
    int w4r = (S_LEN - rhi) >> 2;
#pragma unroll 1
    for (int row = 0; row < 16; row++) {
      float* ar = arow + (size_t)row * S_LEN;
      for (int c4 = tid; c4 < w4l; c4 += 256)
        __builtin_nontemporal_store(fz, (float4_t*)(ar + c4 * 4));
      float* ar2 = ar + rhi;
      for (int c4 = tid; c4 < w4r; c4 += 256)
        __builtin_nontemporal_store(fz, (float4_t*)(ar2 + c4 * 4));
    }
  }
  {
    const half8_t hz = {};
    for (int i = tid; i < 16 * PBS / 8; i += 256) ((half8_t*)Pband)[i] = hz;
    for (int i = tid; i < 16 * PUS / 8; i += 256) ((half8_t*)Pu)[i] = hz;
  }

  // ---- Q fragments (pre-scaled by 1/8 via w_q) ----
  half8_t aq[2];
  {
    const _Float16* qp = Qb + (size_t)(l0 + ln) * DK + quad * 8;
    aq[0] = *(const half8_t*)(qp);
    aq[1] = *(const half8_t*)(qp + 32);
  }

  // ---- RelL[l][j] = (Q/8).(8*rel_k[j+1]) - dec*|j-127| ----
#pragma unroll
  for (int s = 0; s < 4; s++) {
    int nt = wave * 4 + s;
    int j = nt * 16 + ln;
    const _Float16* bp = relk + (size_t)(j + 1) * DK + quad * 8;
    half8_t b0 = *(const half8_t*)bp;
    half8_t b1 = *(const half8_t*)(bp + 32);
    float4_t c = {0.f, 0.f, 0.f, 0.f};
    c = __builtin_amdgcn_mfma_f32_16x16x32_f16(aq[0], b0, c, 0, 0, 0);
    c = __builtin_amdgcn_mfma_f32_16x16x32_f16(aq[1], b1, c, 0, 0, 0);
    float db = dec * fabsf((float)(j - 127));
#pragma unroll
    for (int i = 0; i < 4; i++) scratch[(quad * 4 + i) * RELS + j] = c[i] - db;
  }
  __syncthreads();

  // ---- scores in registers ----
  float4_t sreg[5];
#pragma unroll
  for (int tt = 0; tt < 5; tt++) { sreg[tt][0]=-1e30f; sreg[tt][1]=-1e30f; sreg[tt][2]=-1e30f; sreg[tt][3]=-1e30f; }

#pragma unroll
  for (int tt = 0; tt < 5; tt++) {
    int t = ts + tt;
    if (t < te) {
      int r0 = rlo + t * 16;
      const _Float16* kp = Kb + (size_t)(r0 + ln) * DK + quad * 8;
      half8_t b0 = *(const half8_t*)(kp);
      half8_t b1 = *(const half8_t*)(kp + 32);
      float4_t c = {0.f, 0.f, 0.f, 0.f};
      c = __builtin_amdgcn_mfma_f32_16x16x32_f16(aq[0], b0, c, 0, 0, 0);
      c = __builtin_amdgcn_mfma_f32_16x16x32_f16(aq[1], b1, c, 0, 0, 0);
      int r = r0 + ln;
#pragma unroll
      for (int i = 0; i < 4; i++) {
        int row = quad * 4 + i;
        int dd = r - (l0 + row);
        bool valid = (dd >= -127) && (dd <= 127);
        sreg[tt][i] = valid ? (c[i] + scratch[row * RELS + (dd + 127)]) : -1e30f;
      }
    }
  }

  // ---- softmax stats ----
  float mw[4] = {-1e30f, -1e30f, -1e30f, -1e30f};
#pragma unroll
  for (int tt = 0; tt < 5; tt++)
#pragma unroll
    for (int i = 0; i < 4; i++) mw[i] = fmaxf(mw[i], sreg[tt][i]);
#pragma unroll
  for (int off = 1; off < 16; off <<= 1)
#pragma unroll
    for (int i = 0; i < 4; i++) mw[i] = fmaxf(mw[i], __shfl_xor(mw[i], off, 64));

  float ew[4] = {0.f, 0.f, 0.f, 0.f};
#pragma unroll
  for (int tt = 0; tt < 5; tt++)
#pragma unroll
    for (int i = 0; i < 4; i++) {
      float e = (sreg[tt][i] > -1e29f) ? __expf(sreg[tt][i] - mw[i]) : 0.f;
      sreg[tt][i] = e;
      ew[i] += e;
    }
#pragma unroll
  for (int off = 1; off < 16; off <<= 1)
#pragma unroll
    for (int i = 0; i < 4; i++) ew[i] += __shfl_xor(ew[i], off, 64);

  if (ln == 0) {
#pragma unroll
    for (int i = 0; i < 4; i++) {
      statsM[wave][quad * 4 + i] = mw[i];
      statsZ[wave][quad * 4 + i] = ew[i];
    }
  }
  __syncthreads();   // stats ready; also: last read of RelL was before here

  float scale[4];
#pragma unroll
  for (int i = 0; i < 4; i++) {
    int row = quad * 4 + i;
    float mf = fmaxf(fmaxf(statsM[0][row], statsM[1][row]),
                     fmaxf(statsM[2][row], statsM[3][row]));
    float z = statsZ[0][row] * __expf(statsM[0][row] - mf)
            + statsZ[1][row] * __expf(statsM[1][row] - mf)
            + statsZ[2][row] * __expf(statsM[2][row] - mf)
            + statsZ[3][row] * __expf(statsM[3][row] - mf);
    scale[i] = __expf(mw[i] - mf) / z;
  }

  // ---- write normalized p to Pu and Pband ----
#pragma unroll
  for (int tt = 0; tt < 5; tt++) {
    int t = ts + tt;
    if (t < te) {
      int col = t * 16 + ln;
      int r = rlo + col;
#pragma unroll
      for (int i = 0; i < 4; i++) {
        int row = quad * 4 + i;
        _Float16 ph = (_Float16)(sreg[tt][i] * scale[i]);
        Pu[row * PUS + col] = ph;
        int dd = r - (l0 + row);
        if (dd >= -127 && dd <= 127) Pband[row * PBS + (dd + 127)] = ph;
      }
    }
  }
  __syncthreads();   // P ready; scratch (ex-RelL) now reusable as slabs

  // ---- attn band store: dense, nontemporal ----
  {
    int row = tid >> 4;
    int lc = tid & 15;
    float* ar = arow + (size_t)row * S_LEN + rlo;
    const _Float16* pr = Pu + row * PUS;
    int W4 = W >> 2;
    for (int c4 = lc; c4 < W4; c4 += 16) {
      half4_t hp = *(const half4_t*)(pr + c4 * 4);
      float4_t f;
      f[0] = (float)hp[0]; f[1] = (float)hp[1];
      f[2] = (float)hp[2]; f[3] = (float)hp[3];
      __builtin_nontemporal_store(f, (float4_t*)(ar + c4 * 4));
    }
  }

  // ---- PV via 16x16x32 over 32-wide r chunks ----
  float4_t ctxa[4];
#pragma unroll
  for (int nt = 0; nt < 4; nt++) { ctxa[nt][0]=0.f; ctxa[nt][1]=0.f; ctxa[nt][2]=0.f; ctxa[nt][3]=0.f; }
  {
    int nC = (W + 31) >> 5;
    int cs = (wave * nC) >> 2, ce = ((wave + 1) * nC) >> 2;
    for (int cc2 = cs; cc2 < ce; cc2++) {
      half8_t a = *(const half8_t*)(Pu + ln * PUS + cc2 * 32 + quad * 8);
      int rb = rlo + cc2 * 32 + quad * 8;
#pragma unroll
      for (int nt = 0; nt < 4; nt++) {
        half8_t bv = *(const half8_t*)(Vb + (size_t)(nt * 16 + ln) * S_LEN + rb);
        ctxa[nt] = __builtin_amdgcn_mfma_f32_16x16x32_f16(a, bv, ctxa[nt], 0, 0, 0);
      }
    }
  }

  // ---- rel_v GEMM folded in: rc covers ctx cols wave*16+ln == ctxa[wave] ----
  {
    float4_t rc = {0.f, 0.f, 0.f, 0.f};
#pragma unroll
    for (int cch = 0; cch < 8; cch++) {
      half8_t apb = *(const half8_t*)(Pband + ln * PBS + cch * 32 + quad * 8);
      half8_t bb  = *(const half8_t*)(rvT + (size_t)(wave * 16 + ln) * 256 + cch * 32 + quad * 8);
      rc = __builtin_amdgcn_mfma_f32_16x16x32_f16(apb, bb, rc, 0, 0, 0);
    }
    // static indexing (rule #20): uniform per-wave branch, no divergence
    if (wave == 0)      { ctxa[0][0]+=rc[0]; ctxa[0][1]+=rc[1]; ctxa[0][2]+=rc[2]; ctxa[0][3]+=rc[3]; }
    else if (wave == 1) { ctxa[1][0]+=rc[0]; ctxa[1][1]+=rc[1]; ctxa[1][2]+=rc[2]; ctxa[1][3]+=rc[3]; }
    else if (wave == 2) { ctxa[2][0]+=rc[0]; ctxa[2][1]+=rc[1]; ctxa[2][2]+=rc[2]; ctxa[2][3]+=rc[3]; }
    else                { ctxa[3][0]+=rc[0]; ctxa[3][1]+=rc[1]; ctxa[3][2]+=rc[2]; ctxa[3][3]+=rc[3]; }
  }

  // ---- per-wave slab store (each wave writes its full 16x64 tile) ----
  {
    float* slab = scratch + wave * (16 * SLABS);
#pragma unroll
    for (int nt = 0; nt < 4; nt++)
#pragma unroll
      for (int i = 0; i < 4; i++)
        slab[(quad * 4 + i) * SLABS + nt * 16 + ln] = ctxa[nt][i];
  }
  __syncthreads();

  // ---- reduce 4 slabs -> ctx store (half4 per thread) ----
  {
    int l = tid >> 4, d4 = (tid & 15) * 4;
    const float* s0 = scratch + l * SLABS + d4;
    float4_t v0 = *(const float4_t*)(s0);
    float4_t v1 = *(const float4_t*)(s0 + 16 * SLABS);
    float4_t v2 = *(const float4_t*)(s0 + 32 * SLABS);
    float4_t v3 = *(const float4_t*)(s0 + 48 * SLABS);
    half4_t hv;
    hv[0] = (_Float16)(v0[0] + v1[0] + v2[0] + v3[0]);
    hv[1] = (_Float16)(v0[1] + v1[1] + v2[1] + v3[1]);
    hv[2] = (_Float16)(v0[2] + v1[2] + v2[2] + v3[2]);
    hv[3] = (_Float16)(v0[3] + v1[3] + v2[3] + v3[3]);
    *(half4_t*)(ctx + ((size_t)(b * S_LEN + l0 + l)) * DMODEL + h * DK + d4) = hv;
  }
}

// ---------------- launcher ----------------
extern "C" void kernel_launch(void* const* d_in, const int* in_sizes, int n_in,
                              void* d_out, int out_size, void* d_ws, size_t ws_size,
                              hipStream_t stream) {
  const float* q   = (const float*)d_in[0];
  const float* k   = (const float*)d_in[1];
  const float* v   = (const float*)d_in[2];
  const float* wq  = (const float*)d_in[3];
  const float* wk  = (const float*)d_in[4];
  const float* wv  = (const float*)d_in[5];
  const float* wo  = (const float*)d_in[6];
  const float* bo  = (const float*)d_in[7];
  const float* rk  = (const float*)d_in[8];
  const float* rv  = (const float*)d_in[9];
  const float* td  = (const float*)d_in[10];

  char* ws = (char*)d_ws;
  size_t off = 0;
  auto alloc = [&](size_t bytes) -> void* {
    void* p = ws + off;
    off += (bytes + 255) & ~(size_t)255;
    return p;
  };
  const size_t NTOK = (size_t)BATCH * S_LEN;
  _Float16* Xq  = (_Float16*)alloc(NTOK * DMODEL * 2);
  _Float16* Xk  = (_Float16*)alloc(NTOK * DMODEL * 2);
  _Float16* Xv  = (_Float16*)alloc(NTOK * DMODEL * 2);
  _Float16* Wqh = (_Float16*)alloc((size_t)DMODEL * DMODEL * 2);
  _Float16* Wkh = (_Float16*)alloc((size_t)DMODEL * DMODEL * 2);
  _Float16* Wvh = (_Float16*)alloc((size_t)DMODEL * DMODEL * 2);
  _Float16* Woh = (_Float16*)alloc((size_t)DMODEL * DMODEL * 2);
  _Float16* Qh  = (_Float16*)alloc(NTOK * DMODEL * 2);
  _Float16* Kh  = (_Float16*)alloc(NTOK * DMODEL * 2);
  _Float16* VtG = (_Float16*)alloc(NTOK * DMODEL * 2 + 256);
  _Float16* Ctx = (_Float16*)alloc(NTOK * DMODEL * 2);
  _Float16* Rkh = (_Float16*)alloc((size_t)257 * 64 * 2);
  _Float16* RvT = (_Float16*)alloc((size_t)64 * 256 * 2);

  CvtArgs ca;
  ca.r[0] = {q,  Xq,  (int)(NTOK * DMODEL / 4), 1.f};
  ca.r[1] = {k,  Xk,  (int)(NTOK * DMODEL / 4), 1.f};
  ca.r[2] = {v,  Xv,  (int)(NTOK * DMODEL / 4), 1.f};
  ca.r[3] = {wq, Wqh, DMODEL * DMODEL / 4, 0.125f};  // fold 1/sqrt(dk)
  ca.r[4] = {wk, Wkh, DMODEL * DMODEL / 4, 1.f};
  ca.r[5] = {wv, Wvh, DMODEL * DMODEL / 4, 1.f};
  ca.r[6] = {wo, Woh, DMODEL * DMODEL / 4, 1.f};
  ca.r[7] = {rk, Rkh, 257 * 64 / 4, 8.f};            // rel_k * 8 compensates
  cvt_all_kernel<<<dim3(512, 8), dim3(256), 0, stream>>>(ca);
  build_rvT_kernel<<<dim3(64), dim3(256), 0, stream>>>(rv, RvT);

  QkvArgs qa;
  qa.A[0] = Xq; qa.A[1] = Xk; qa.A[2] = Xv;
  qa.B[0] = Wqh; qa.B[1] = Wkh; qa.B[2] = Wvh;
  qa.dst[0] = Qh; qa.dst[1] = Kh; qa.dst[2] = VtG;
  gemm_qkv<<<dim3(64, 8, 3), dim3(256), 0, stream>>>(qa);

  float* attn_out = (float*)d_out + NTOK * DMODEL;
  attn4_kernel<<<dim3(BATCH * NHEADS * (S_LEN / 16)), dim3(256), 0, stream>>>(
      Qh, Kh, VtG, Rkh, RvT, td, attn_out, Ctx);

  gemm_out<<<dim3(64, 8), dim3(256), 0, stream>>>(Ctx, Woh, (float*)d_out, bo);
}